// Round 1
// baseline (256.590 us; speedup 1.0000x reference)
//
#include <hip/hip_runtime.h>

// RoIAlign: features (B=4, C=256, H=200, W=200) f32, rois (R,5) f32,
// out (R, C, 7, 7) f32.  SCALE=0.25, AH=AW=7, legacy (x2-x1+1) semantics.

#define C_    256
#define H_    200
#define W_    200
#define NBIN  49     // 7*7
#define SCALE_ 0.25f

// ---------------- kernel 1: per-(roi,bin) geometry table -------------------
// table[i] = { hr, wr, as_float(h0 | w0<<8 | b<<16 | valid<<18), 0 }
__global__ __launch_bounds__(256) void roi_precompute(
        const float* __restrict__ rois, float4* __restrict__ table, int nbins) {
    int i = blockIdx.x * 256 + threadIdx.x;
    if (i >= nbins) return;
    int r   = i / NBIN;
    int bin = i - r * NBIN;
    int ph  = bin / 7;
    int pw  = bin - ph * 7;

    float bf = rois[r * 5 + 0];
    float x1 = rois[r * 5 + 1] * SCALE_;
    float y1 = rois[r * 5 + 2] * SCALE_;
    float x2 = rois[r * 5 + 3] * SCALE_;
    float y2 = rois[r * 5 + 4] * SCALE_;

    float roi_w = fmaxf(x2 - x1 + 1.0f, 0.0f);
    float roi_h = fmaxf(y2 - y1 + 1.0f, 0.0f);
    float bin_h = roi_h / 6.0f;   // AH-1
    float bin_w = roi_w / 6.0f;   // AW-1

    float h = y1 + (float)ph * bin_h;
    float w = x1 + (float)pw * bin_w;

    bool valid = (h >= 0.0f) && (h < (float)H_) && (w >= 0.0f) && (w < (float)W_);

    float h0f = fmaxf(fminf(floorf(h), (float)(H_ - 2)), 0.0f);
    float w0f = fmaxf(fminf(floorf(w), (float)(W_ - 2)), 0.0f);
    int h0 = (int)h0f;
    int w0 = (int)w0f;
    float hr = h - h0f;
    float wr = w - w0f;
    int b = (int)bf;

    int packed = h0 | (w0 << 8) | (b << 16) | ((valid ? 1 : 0) << 18);
    table[i] = make_float4(hr, wr, __int_as_float(packed), 0.0f);
}

// ---------------- kernel 2: main gather, 1 thread per output element -------
// flat out index = ((r*C + c)*49 + bin)  -> fully coalesced stores.
__global__ __launch_bounds__(256) void roi_main(
        const float* __restrict__ feat, const float4* __restrict__ table,
        float* __restrict__ out, int total) {
    int idx = blockIdx.x * 256 + threadIdx.x;
    if (idx >= total) return;

    unsigned u   = (unsigned)idx;
    unsigned bin = u % (unsigned)NBIN;
    unsigned rc  = u / (unsigned)NBIN;   // r*256 + c
    unsigned c   = rc & 255u;
    unsigned r   = rc >> 8;

    float4 t   = table[r * NBIN + bin];
    int packed = __float_as_int(t.z);
    int h0 = packed & 255;
    int w0 = (packed >> 8) & 255;
    int b  = (packed >> 16) & 3;
    float valid = (float)((packed >> 18) & 1);

    const float* p = feat + ((size_t)(b * C_ + (int)c)) * (size_t)(H_ * W_)
                          + (size_t)(h0 * W_ + w0);
    float v00 = p[0];
    float v01 = p[1];
    float v10 = p[W_];
    float v11 = p[W_ + 1];

    float hr = t.x, wr = t.y;
    float top = fmaf(wr, v01 - v00, v00);
    float bot = fmaf(wr, v11 - v10, v10);
    float val = fmaf(hr, bot - top, top);

    out[idx] = val * valid;
}

// ---------------- fallback: fused (no workspace table) ---------------------
__global__ __launch_bounds__(256) void roi_fused(
        const float* __restrict__ feat, const float* __restrict__ rois,
        float* __restrict__ out, int total) {
    int idx = blockIdx.x * 256 + threadIdx.x;
    if (idx >= total) return;

    unsigned u   = (unsigned)idx;
    unsigned bin = u % (unsigned)NBIN;
    unsigned rc  = u / (unsigned)NBIN;
    unsigned c   = rc & 255u;
    unsigned r   = rc >> 8;
    int ph = bin / 7;
    int pw = bin - ph * 7;

    float bf = rois[r * 5 + 0];
    float x1 = rois[r * 5 + 1] * SCALE_;
    float y1 = rois[r * 5 + 2] * SCALE_;
    float x2 = rois[r * 5 + 3] * SCALE_;
    float y2 = rois[r * 5 + 4] * SCALE_;

    float roi_w = fmaxf(x2 - x1 + 1.0f, 0.0f);
    float roi_h = fmaxf(y2 - y1 + 1.0f, 0.0f);
    float h = y1 + (float)ph * (roi_h / 6.0f);
    float w = x1 + (float)pw * (roi_w / 6.0f);

    float valid = ((h >= 0.0f) && (h < (float)H_) && (w >= 0.0f) && (w < (float)W_))
                      ? 1.0f : 0.0f;

    float h0f = fmaxf(fminf(floorf(h), (float)(H_ - 2)), 0.0f);
    float w0f = fmaxf(fminf(floorf(w), (float)(W_ - 2)), 0.0f);
    int h0 = (int)h0f;
    int w0 = (int)w0f;
    float hr = h - h0f;
    float wr = w - w0f;
    int b = (int)bf;

    const float* p = feat + ((size_t)(b * C_ + (int)c)) * (size_t)(H_ * W_)
                          + (size_t)(h0 * W_ + w0);
    float v00 = p[0];
    float v01 = p[1];
    float v10 = p[W_];
    float v11 = p[W_ + 1];

    float top = fmaf(wr, v01 - v00, v00);
    float bot = fmaf(wr, v11 - v10, v10);
    float val = fmaf(hr, bot - top, top);

    out[idx] = val * valid;
}

extern "C" void kernel_launch(void* const* d_in, const int* in_sizes, int n_in,
                              void* d_out, int out_size, void* d_ws, size_t ws_size,
                              hipStream_t stream) {
    const float* feat = (const float*)d_in[0];
    const float* rois = (const float*)d_in[1];
    float* out = (float*)d_out;

    int R     = in_sizes[1] / 5;
    int nbins = R * NBIN;
    int total = R * C_ * NBIN;   // == out_size

    if ((size_t)nbins * sizeof(float4) <= ws_size) {
        float4* table = (float4*)d_ws;
        roi_precompute<<<(nbins + 255) / 256, 256, 0, stream>>>(rois, table, nbins);
        roi_main<<<(total + 255) / 256, 256, 0, stream>>>(feat, table, out, total);
    } else {
        roi_fused<<<(total + 255) / 256, 256, 0, stream>>>(feat, rois, out, total);
    }
}